// Round 1
// baseline (136.139 us; speedup 1.0000x reference)
//
#include <hip/hip_runtime.h>
#include <math.h>

// ---------------------------------------------------------------------------
// RegressionLoss, R4: single fused kernel, ZERO workspace use.
//
// R3 analysis: the timed region is dominated by the harness's 256 MiB
// workspace re-poison fill (39.7 us @ 84% HBM peak, top-5 dispatches are all
// fillBufferAligned). R4 moves all intermediates (992 chamfer halves + 1024
// dots, 8 KB total) into __device__ globals and fuses pairs+finish into one
// launch via a last-block-done ticket (atomic counter, modulo 1024 so no
// per-iteration reset is needed across graph replays). No block ever waits
// on another -> no residency/deadlock hazard.
//
// Chamfer inner loop switched to the reference's own expansion
// d2 = |p|^2 + |q|^2 - 2 p.q : LDS stages (-2x,-2y,-2z,|q|^2) so each inner
// point costs 3 packed-FMA + 1 min (10 VALU / 4 pts vs 16 in R3).
// ---------------------------------------------------------------------------

typedef float f32x2 __attribute__((ext_vector_type(2)));

__device__ float g_cdHalf[992];      // directional chamfer halves
__device__ float g_dots[1024];       // 32x32 normalized inner products
__device__ unsigned int g_counter = 0;   // monotone; ticket = old & 1023

__device__ __forceinline__ float waveReduceSum64(float v) {
    #pragma unroll
    for (int m = 32; m > 0; m >>= 1) v += __shfl_xor(v, m, 64);
    return v;
}

__global__ __launch_bounds__(256, 4) void fused_kernel(const float* __restrict__ emb,
                                                       const float* __restrict__ xyz,
                                                       float* __restrict__ out) {
    const int t = threadIdx.x;
    const int b = blockIdx.x;

    __shared__ __align__(16) float S[4 * 256];
    __shared__ float red[4];
    __shared__ unsigned int ticket;

    if (b < 992) {
        // ---- directional chamfer half ----
        const int pb  = b >> 1;
        const int dir = b & 1;
        int ii = 0, rem = pb;                       // strict upper-tri decode
        while (rem >= (31 - ii)) { rem -= (31 - ii); ++ii; }
        const int jj = ii + 1 + rem;
        const int outer = dir ? jj : ii;
        const int inner = dir ? ii : jj;

        const float* Po = xyz + (32 + outer) * 768;   // shapes = xyz[32:]
        const float* Pi = xyz + (32 + inner) * 768;

        // stage inner shape as (-2x, -2y, -2z, |q|^2) SoA
        const float qx = Pi[3*t], qy = Pi[3*t+1], qz = Pi[3*t+2];
        S[t]       = -2.0f * qx;
        S[t + 256] = -2.0f * qy;
        S[t + 512] = -2.0f * qz;
        S[t + 768] = qx*qx + qy*qy + qz*qz;
        const float px = Po[3*t], py = Po[3*t+1], pz = Po[3*t+2];
        const float pp = px*px + py*py + pz*pz;
        __syncthreads();

        const f32x2 Px = {px, px}, Py = {py, py}, Pz = {pz, pz};
        f32x2 m0 = {3.4e38f, 3.4e38f}, m1 = {3.4e38f, 3.4e38f};

        #pragma unroll 4
        for (int s = 0; s < 256; s += 4) {
            const float4 vx = *(const float4*)&S[s];
            const float4 vy = *(const float4*)&S[s + 256];
            const float4 vz = *(const float4*)&S[s + 512];
            const float4 vw = *(const float4*)&S[s + 768];
            {   // points s, s+1:  e = |q|^2 - 2 p.q  (3 packed FMA)
                f32x2 e = {vw.x, vw.y};
                e = Pz * (f32x2){vz.x, vz.y} + e;
                e = Py * (f32x2){vy.x, vy.y} + e;
                e = Px * (f32x2){vx.x, vx.y} + e;
                m0.x = fminf(m0.x, e.x); m0.y = fminf(m0.y, e.y);
            }
            {   // points s+2, s+3
                f32x2 e = {vw.z, vw.w};
                e = Pz * (f32x2){vz.z, vz.w} + e;
                e = Py * (f32x2){vy.z, vy.w} + e;
                e = Px * (f32x2){vx.z, vx.w} + e;
                m1.x = fminf(m1.x, e.x); m1.y = fminf(m1.y, e.y);
            }
        }
        const float mn = fminf(fminf(m0.x, m0.y), fminf(m1.x, m1.y)) + pp;

        float v = waveReduceSum64(mn);
        if ((t & 63) == 0) red[t >> 6] = v;
        __syncthreads();
        if (t == 0) {
            const float val = (red[0] + red[1] + red[2] + red[3]) * (1.0f / 256.0f);
            __hip_atomic_store(&g_cdHalf[b], val, __ATOMIC_RELAXED, __HIP_MEMORY_SCOPE_AGENT);
        }
    } else {
        // ---- dot row i: dots[i*32+j] = cos(emb_i, emb_{32+j}) ----
        const int i = b - 992;
        float* rowi = S;                       // 512 floats
        const float* Ei = emb + i * 512;
        rowi[t]       = Ei[t];
        rowi[t + 256] = Ei[t + 256];
        __syncthreads();

        const int w    = t >> 6;
        const int lane = t & 63;

        float ni = 0.0f;
        #pragma unroll
        for (int m = 0; m < 8; ++m) { float a = rowi[lane + 64*m]; ni += a*a; }
        ni = waveReduceSum64(ni);

        for (int j = w; j < 32; j += 4) {
            const float* Ej = emb + (32 + j) * 512;
            float dot = 0.0f, nj = 0.0f;
            #pragma unroll
            for (int m = 0; m < 8; ++m) {
                float a  = rowi[lane + 64*m];
                float bv = Ej[lane + 64*m];
                dot += a * bv;
                nj  += bv * bv;
            }
            dot = waveReduceSum64(dot);
            nj  = waveReduceSum64(nj);
            if (lane == 0)
                __hip_atomic_store(&g_dots[i * 32 + j], dot * rsqrtf(ni * nj),
                                   __ATOMIC_RELAXED, __HIP_MEMORY_SCOPE_AGENT);
        }
    }

    // ---- completion ticket: last of 1024 blocks runs the finish ----
    __threadfence();                            // release this thread's stores
    __syncthreads();
    if (t == 0)
        ticket = __hip_atomic_fetch_add(&g_counter, 1u, __ATOMIC_ACQ_REL,
                                        __HIP_MEMORY_SCOPE_AGENT) & 1023u;
    __syncthreads();
    if (ticket != 1023u) return;
    __threadfence();                            // acquire

    // ---- finish: 256 threads, 4 (i,j) entries each; 8 lanes per row ----
    const int fi = t >> 3;                      // row 0..31
    const int jb = (t & 7) << 2;                // col base
    const float inv_denom = 1.0f / (2.0f * (0.997f / 3.0f) * (0.997f / 3.0f));

    float sv[4], hv[4];
    #pragma unroll
    for (int k = 0; k < 4; ++k) {
        const int j = jb + k;
        float c = 0.0f;                         // chamfer(self) == 0
        if (fi != j) {
            const int a  = fi < j ? fi : j;
            const int bb = fi < j ? j : fi;
            const int pq = a * 31 - (a * (a - 1)) / 2 + (bb - a - 1);
            const float c0 = __hip_atomic_load(&g_cdHalf[2*pq],     __ATOMIC_RELAXED, __HIP_MEMORY_SCOPE_AGENT);
            const float c1 = __hip_atomic_load(&g_cdHalf[2*pq + 1], __ATOMIC_RELAXED, __HIP_MEMORY_SCOPE_AGENT);
            c = c0 + c1;
        }
        sv[k] = -(c * c) * inv_denom;
        hv[k] = __hip_atomic_load(&g_dots[fi * 32 + jb + k], __ATOMIC_RELAXED, __HIP_MEMORY_SCOPE_AGENT);
    }

    // row softmaxes: reduce 4 locals, then across the 8-lane group (xor 1,2,4)
    float mx1 = fmaxf(fmaxf(sv[0], sv[1]), fmaxf(sv[2], sv[3]));
    float mx2 = fmaxf(fmaxf(hv[0], hv[1]), fmaxf(hv[2], hv[3]));
    #pragma unroll
    for (int m = 1; m <= 4; m <<= 1) {
        mx1 = fmaxf(mx1, __shfl_xor(mx1, m, 64));
        mx2 = fmaxf(mx2, __shfl_xor(mx2, m, 64));
    }
    float e1[4], e2[4], sum1 = 0.0f, sum2 = 0.0f;
    #pragma unroll
    for (int k = 0; k < 4; ++k) {
        e1[k] = expf(sv[k] - mx1); sum1 += e1[k];
        e2[k] = expf(hv[k] - mx2); sum2 += e2[k];
    }
    #pragma unroll
    for (int m = 1; m <= 4; m <<= 1) {
        sum1 += __shfl_xor(sum1, m, 64);
        sum2 += __shfl_xor(sum2, m, 64);
    }
    float acc = 0.0f;
    #pragma unroll
    for (int k = 0; k < 4; ++k) acc += fabsf(e2[k] / sum2 - e1[k] / sum1);

    acc = waveReduceSum64(acc);
    if ((t & 63) == 0) red[t >> 6] = acc;
    __syncthreads();
    if (t == 0)
        out[0] = (red[0] + red[1] + red[2] + red[3]) * (1.0f / 1024.0f);
}

extern "C" void kernel_launch(void* const* d_in, const int* in_sizes, int n_in,
                              void* d_out, int out_size, void* d_ws, size_t ws_size,
                              hipStream_t stream) {
    (void)in_sizes; (void)n_in; (void)out_size; (void)d_ws; (void)ws_size;
    const float* emb = (const float*)d_in[0];   // 64 x 512
    const float* xyz = (const float*)d_in[1];   // 64 x 256 x 3
    float* out = (float*)d_out;

    hipLaunchKernelGGL(fused_kernel, dim3(1024), dim3(256), 0, stream, emb, xyz, out);
}

// Round 2
// 75.236 us; speedup vs baseline: 1.8095x; 1.8095x over previous
//
#include <hip/hip_runtime.h>
#include <math.h>

// ---------------------------------------------------------------------------
// RegressionLoss, R5: fused single kernel, zero workspace, NO device fences.
//
// R4 post-mortem: the 256 MiB workspace poison fill (39.7 us) is
// unconditional, and the per-thread __threadfence() at the ticket compiled
// to buffer_wbl2/buffer_inv L2-maintenance ops that serialized at each
// XCD's L2 (~65 us of stall, VALUBusy 4%). R5 keeps the fused ticket design
// but drops ALL fences:
//   - intermediates are written with relaxed AGENT-scope atomic stores
//     (sc1 -> bypass non-coherent per-XCD L2, land at the shared coherence
//     point),
//   - an explicit s_waitcnt vmcnt(0) before the pre-ticket barrier
//     guarantees every wave's stores have COMPLETED (acked by the coherence
//     point) before thread 0 increments the ticket,
//   - the last block reads them back with relaxed AGENT-scope atomic loads
//     (sc1 -> bypass stale L1/L2).
// No block waits on another; the 1024th ticket holder runs the finish.
// ---------------------------------------------------------------------------

typedef float f32x2 __attribute__((ext_vector_type(2)));

__device__ float g_cdHalf[992];          // directional chamfer halves
__device__ float g_dots[1024];           // 32x32 normalized inner products
__device__ unsigned int g_counter = 0;   // monotone; ticket = old & 1023

__device__ __forceinline__ float waveReduceSum64(float v) {
    #pragma unroll
    for (int m = 32; m > 0; m >>= 1) v += __shfl_xor(v, m, 64);
    return v;
}

__global__ __launch_bounds__(256, 4) void fused_kernel(const float* __restrict__ emb,
                                                       const float* __restrict__ xyz,
                                                       float* __restrict__ out) {
    const int t = threadIdx.x;
    const int b = blockIdx.x;

    __shared__ __align__(16) float S[4 * 256];
    __shared__ float red[4];
    __shared__ unsigned int ticket;

    if (b < 992) {
        // ---- directional chamfer half ----
        const int pb  = b >> 1;
        const int dir = b & 1;
        int ii = 0, rem = pb;                       // strict upper-tri decode
        while (rem >= (31 - ii)) { rem -= (31 - ii); ++ii; }
        const int jj = ii + 1 + rem;
        const int outer = dir ? jj : ii;
        const int inner = dir ? ii : jj;

        const float* Po = xyz + (32 + outer) * 768;   // shapes = xyz[32:]
        const float* Pi = xyz + (32 + inner) * 768;

        // stage inner shape as (-2x, -2y, -2z, |q|^2) SoA
        const float qx = Pi[3*t], qy = Pi[3*t+1], qz = Pi[3*t+2];
        S[t]       = -2.0f * qx;
        S[t + 256] = -2.0f * qy;
        S[t + 512] = -2.0f * qz;
        S[t + 768] = qx*qx + qy*qy + qz*qz;
        const float px = Po[3*t], py = Po[3*t+1], pz = Po[3*t+2];
        const float pp = px*px + py*py + pz*pz;
        __syncthreads();

        const f32x2 Px = {px, px}, Py = {py, py}, Pz = {pz, pz};
        f32x2 m0 = {3.4e38f, 3.4e38f}, m1 = {3.4e38f, 3.4e38f};

        #pragma unroll 4
        for (int s = 0; s < 256; s += 4) {
            const float4 vx = *(const float4*)&S[s];         // broadcast b128
            const float4 vy = *(const float4*)&S[s + 256];
            const float4 vz = *(const float4*)&S[s + 512];
            const float4 vw = *(const float4*)&S[s + 768];
            {   // points s, s+1:  e = |q|^2 - 2 p.q  (3 packed FMA)
                f32x2 e = {vw.x, vw.y};
                e = Pz * (f32x2){vz.x, vz.y} + e;
                e = Py * (f32x2){vy.x, vy.y} + e;
                e = Px * (f32x2){vx.x, vx.y} + e;
                m0.x = fminf(m0.x, e.x); m0.y = fminf(m0.y, e.y);
            }
            {   // points s+2, s+3
                f32x2 e = {vw.z, vw.w};
                e = Pz * (f32x2){vz.z, vz.w} + e;
                e = Py * (f32x2){vy.z, vy.w} + e;
                e = Px * (f32x2){vx.z, vx.w} + e;
                m1.x = fminf(m1.x, e.x); m1.y = fminf(m1.y, e.y);
            }
        }
        const float mn = fminf(fminf(m0.x, m0.y), fminf(m1.x, m1.y)) + pp;

        float v = waveReduceSum64(mn);
        if ((t & 63) == 0) red[t >> 6] = v;
        __syncthreads();
        if (t == 0) {
            const float val = (red[0] + red[1] + red[2] + red[3]) * (1.0f / 256.0f);
            __hip_atomic_store(&g_cdHalf[b], val, __ATOMIC_RELAXED, __HIP_MEMORY_SCOPE_AGENT);
        }
    } else {
        // ---- dot row i: dots[i*32+j] = cos(emb_i, emb_{32+j}) ----
        const int i = b - 992;
        float* rowi = S;                       // 512 floats
        const float* Ei = emb + i * 512;
        rowi[t]       = Ei[t];
        rowi[t + 256] = Ei[t + 256];
        __syncthreads();

        const int w    = t >> 6;
        const int lane = t & 63;

        float ni = 0.0f;
        #pragma unroll
        for (int m = 0; m < 8; ++m) { float a = rowi[lane + 64*m]; ni += a*a; }
        ni = waveReduceSum64(ni);

        for (int j = w; j < 32; j += 4) {
            const float* Ej = emb + (32 + j) * 512;
            float dot = 0.0f, nj = 0.0f;
            #pragma unroll
            for (int m = 0; m < 8; ++m) {
                float a  = rowi[lane + 64*m];
                float bv = Ej[lane + 64*m];
                dot += a * bv;
                nj  += bv * bv;
            }
            dot = waveReduceSum64(dot);
            nj  = waveReduceSum64(nj);
            if (lane == 0)
                __hip_atomic_store(&g_dots[i * 32 + j], dot * rsqrtf(ni * nj),
                                   __ATOMIC_RELAXED, __HIP_MEMORY_SCOPE_AGENT);
        }
    }

    // ---- completion ticket (NO fences): force every wave's stores to have
    // completed at the coherence point before the barrier, then RMW.
    asm volatile("s_waitcnt vmcnt(0)" ::: "memory");
    __syncthreads();
    if (t == 0)
        ticket = __hip_atomic_fetch_add(&g_counter, 1u, __ATOMIC_RELAXED,
                                        __HIP_MEMORY_SCOPE_AGENT) & 1023u;
    __syncthreads();
    if (ticket != 1023u) return;

    // ---- finish (last block only): 256 threads, 4 (i,j) entries each ----
    const int fi = t >> 3;                      // row 0..31
    const int jb = (t & 7) << 2;                // col base
    const float inv_denom = 1.0f / (2.0f * (0.997f / 3.0f) * (0.997f / 3.0f));

    float sv[4], hv[4];
    #pragma unroll
    for (int k = 0; k < 4; ++k) {
        const int j = jb + k;
        float c = 0.0f;                         // chamfer(self) == 0
        if (fi != j) {
            const int a  = fi < j ? fi : j;
            const int bb = fi < j ? j : fi;
            const int pq = a * 31 - (a * (a - 1)) / 2 + (bb - a - 1);
            const float c0 = __hip_atomic_load(&g_cdHalf[2*pq],     __ATOMIC_RELAXED, __HIP_MEMORY_SCOPE_AGENT);
            const float c1 = __hip_atomic_load(&g_cdHalf[2*pq + 1], __ATOMIC_RELAXED, __HIP_MEMORY_SCOPE_AGENT);
            c = c0 + c1;
        }
        sv[k] = -(c * c) * inv_denom;
        hv[k] = __hip_atomic_load(&g_dots[fi * 32 + jb + k], __ATOMIC_RELAXED, __HIP_MEMORY_SCOPE_AGENT);
    }

    // row softmaxes: reduce 4 locals, then across the 8-lane row group
    float mx1 = fmaxf(fmaxf(sv[0], sv[1]), fmaxf(sv[2], sv[3]));
    float mx2 = fmaxf(fmaxf(hv[0], hv[1]), fmaxf(hv[2], hv[3]));
    #pragma unroll
    for (int m = 1; m <= 4; m <<= 1) {
        mx1 = fmaxf(mx1, __shfl_xor(mx1, m, 64));
        mx2 = fmaxf(mx2, __shfl_xor(mx2, m, 64));
    }
    float e1[4], e2[4], sum1 = 0.0f, sum2 = 0.0f;
    #pragma unroll
    for (int k = 0; k < 4; ++k) {
        e1[k] = expf(sv[k] - mx1); sum1 += e1[k];
        e2[k] = expf(hv[k] - mx2); sum2 += e2[k];
    }
    #pragma unroll
    for (int m = 1; m <= 4; m <<= 1) {
        sum1 += __shfl_xor(sum1, m, 64);
        sum2 += __shfl_xor(sum2, m, 64);
    }
    float acc = 0.0f;
    #pragma unroll
    for (int k = 0; k < 4; ++k) acc += fabsf(e2[k] / sum2 - e1[k] / sum1);

    acc = waveReduceSum64(acc);
    if ((t & 63) == 0) red[t >> 6] = acc;
    __syncthreads();
    if (t == 0)
        out[0] = (red[0] + red[1] + red[2] + red[3]) * (1.0f / 1024.0f);
}

extern "C" void kernel_launch(void* const* d_in, const int* in_sizes, int n_in,
                              void* d_out, int out_size, void* d_ws, size_t ws_size,
                              hipStream_t stream) {
    (void)in_sizes; (void)n_in; (void)out_size; (void)d_ws; (void)ws_size;
    const float* emb = (const float*)d_in[0];   // 64 x 512
    const float* xyz = (const float*)d_in[1];   // 64 x 256 x 3
    float* out = (float*)d_out;

    hipLaunchKernelGGL(fused_kernel, dim3(1024), dim3(256), 0, stream, emb, xyz, out);
}

// Round 3
// 67.188 us; speedup vs baseline: 2.0262x; 1.1198x over previous
//
#include <hip/hip_runtime.h>
#include <math.h>

// ---------------------------------------------------------------------------
// RegressionLoss, R6: back to two plain launches (R3 structure), new chamfer.
//
// Facts from R4/R5: the 256 MiB workspace poison fill (~40 us) is
// unconditional -> using d_ws is free; device-scope atomics/fences are a
// net loss vs a second launch. R3's pairs_kernel was LDS-return-bus bound:
// broadcast ds_read_b128 of the (wave-uniform!) inner shape moved
// 64x16 B/instr on the LDS return bus (~15 us/CU-integral).
//
// R6 chamfer: inner shape streamed via UNIFORM loads (readfirstlane-forced
// uniform pointer -> scalar/L1-broadcast path, ZERO LDS), outer points
// packed 4/lane in f32x2 pairs -> one wave = one directional pair.
// d2 = |p|^2 + (|q|^2 - 2 p.q): the -2 is folded into per-lane outer
// coords; |q|^2 computed once per inner point (3 VALU); per inner point
// ~16 VALU for 256 point-pair evals. 992 waves = 248 blocks + 32 dot-row
// blocks in the same launch; finish kernel unchanged from R3 (verified).
// ---------------------------------------------------------------------------

typedef float f32x2 __attribute__((ext_vector_type(2)));

__device__ __forceinline__ float waveReduceSum64(float v) {
    #pragma unroll
    for (int m = 32; m > 0; m >>= 1) v += __shfl_xor(v, m, 64);
    return v;
}

// grid 280 x 256:
//   blocks [0,248):   4 directional chamfer pairs per block (one per wave)
//   blocks [248,280): dot row i = b-248 -> dots[i*32+j]
__global__ __launch_bounds__(256) void pairs_kernel(const float* __restrict__ emb,
                                                    const float* __restrict__ xyz,
                                                    float* __restrict__ cdHalf,
                                                    float* __restrict__ dots) {
    const int t = threadIdx.x;
    const int b = blockIdx.x;

    __shared__ float S[512];

    if (b < 248) {
        const int w    = t >> 6;
        const int lane = t & 63;
        // wave-uniform pair id, forced into SGPR so downstream addressing is
        // provably uniform (enables scalar loads of the inner shape)
        const int pairIdx = __builtin_amdgcn_readfirstlane((b << 2) | w);  // 0..991
        const int pb  = pairIdx >> 1;
        const int dir = pairIdx & 1;
        int ii = 0, rem = pb;                      // strict upper-tri decode
        while (rem >= (31 - ii)) { rem -= (31 - ii); ++ii; }
        const int jj = ii + 1 + rem;
        const int outer = dir ? jj : ii;
        const int inner = dir ? ii : jj;

        const float* Po = xyz + (32 + outer) * 768;   // shapes = xyz[32:]
        const float* Qf = xyz + (32 + inner) * 768;   // uniform per wave

        // 4 outer points per lane: lane, lane+64, lane+128, lane+192
        float px[4], py[4], pz[4], pp[4];
        #pragma unroll
        for (int k = 0; k < 4; ++k) {
            const float* P = Po + 3 * (lane + 64 * k);
            px[k] = P[0]; py[k] = P[1]; pz[k] = P[2];
            pp[k] = px[k] * px[k] + py[k] * py[k] + pz[k] * pz[k];
        }
        // fold -2 into the outer coords: e = |q|^2 + X*qx + Y*qy + Z*qz
        const f32x2 X01 = {-2.f * px[0], -2.f * px[1]}, X23 = {-2.f * px[2], -2.f * px[3]};
        const f32x2 Y01 = {-2.f * py[0], -2.f * py[1]}, Y23 = {-2.f * py[2], -2.f * py[3]};
        const f32x2 Z01 = {-2.f * pz[0], -2.f * pz[1]}, Z23 = {-2.f * pz[2], -2.f * pz[3]};

        f32x2 m01 = {3.4e38f, 3.4e38f}, m23 = {3.4e38f, 3.4e38f};

        #pragma unroll 8
        for (int s = 0; s < 256; ++s) {
            const float qx = Qf[3 * s];
            const float qy = Qf[3 * s + 1];
            const float qz = Qf[3 * s + 2];
            const float qw = qx * qx + qy * qy + qz * qz;
            const f32x2 QX = {qx, qx}, QY = {qy, qy}, QZ = {qz, qz}, QW = {qw, qw};
            f32x2 e01 = Z01 * QZ + QW;
            e01 = Y01 * QY + e01;
            e01 = X01 * QX + e01;
            f32x2 e23 = Z23 * QZ + QW;
            e23 = Y23 * QY + e23;
            e23 = X23 * QX + e23;
            m01.x = fminf(m01.x, e01.x); m01.y = fminf(m01.y, e01.y);
            m23.x = fminf(m23.x, e23.x); m23.y = fminf(m23.y, e23.y);
        }

        float ssum = (m01.x + pp[0]) + (m01.y + pp[1]) +
                     (m23.x + pp[2]) + (m23.y + pp[3]);
        ssum = waveReduceSum64(ssum);
        if (lane == 0) cdHalf[pairIdx] = ssum * (1.0f / 256.0f);
    } else {
        // ---- dot row i: dots[i*32+j] = cos(emb_i, emb_{32+j}) ----
        const int i = b - 248;
        float* rowi = S;                       // 512 floats
        const float* Ei = emb + i * 512;
        rowi[t]       = Ei[t];
        rowi[t + 256] = Ei[t + 256];
        __syncthreads();

        const int w    = t >> 6;
        const int lane = t & 63;

        float ni = 0.0f;
        #pragma unroll
        for (int m = 0; m < 8; ++m) { float a = rowi[lane + 64 * m]; ni += a * a; }
        ni = waveReduceSum64(ni);

        for (int j = w; j < 32; j += 4) {
            const float* Ej = emb + (32 + j) * 512;
            float dot = 0.0f, nj = 0.0f;
            #pragma unroll
            for (int m = 0; m < 8; ++m) {
                float a  = rowi[lane + 64 * m];
                float bv = Ej[lane + 64 * m];
                dot += a * bv;
                nj  += bv * bv;
            }
            dot = waveReduceSum64(dot);
            nj  = waveReduceSum64(nj);
            if (lane == 0) dots[i * 32 + j] = dot * rsqrtf(ni * nj);
        }
    }
}

// 1 block x 1024 threads: assemble cd, softmaxes, mean abs diff (R3-verified)
__global__ __launch_bounds__(1024) void finish_kernel(const float* __restrict__ cdHalf,
                                                      const float* __restrict__ dots,
                                                      float* __restrict__ out) {
    const int t = threadIdx.x;   // t = i*32 + j ; width-32 segments == rows
    const int i = t >> 5;
    const int j = t & 31;
    const float inv_denom = 1.0f / (2.0f * (0.997f / 3.0f) * (0.997f / 3.0f));

    float c;
    if (i == j) {
        c = 0.0f;                 // chamfer(self) == 0
    } else {
        const int a  = min(i, j), bb = max(i, j);
        const int pb = a * 31 - (a * (a - 1)) / 2 + (bb - a - 1);
        c = cdHalf[2 * pb] + cdHalf[2 * pb + 1];
    }
    float s = -(c * c) * inv_denom;
    float h = dots[t];

    float m1 = s;
    #pragma unroll
    for (int k = 16; k > 0; k >>= 1) m1 = fmaxf(m1, __shfl_xor(m1, k, 32));
    float e1 = expf(s - m1);
    float sum1 = e1;
    #pragma unroll
    for (int k = 16; k > 0; k >>= 1) sum1 += __shfl_xor(sum1, k, 32);
    float p = e1 / sum1;

    float m2 = h;
    #pragma unroll
    for (int k = 16; k > 0; k >>= 1) m2 = fmaxf(m2, __shfl_xor(m2, k, 32));
    float e2 = expf(h - m2);
    float sum2 = e2;
    #pragma unroll
    for (int k = 16; k > 0; k >>= 1) sum2 += __shfl_xor(sum2, k, 32);
    float ph = e2 / sum2;

    float a = fabsf(ph - p);
    a = waveReduceSum64(a);

    __shared__ float red[16];
    if ((t & 63) == 0) red[t >> 6] = a;
    __syncthreads();
    if (t == 0) {
        float tot = 0.0f;
        #pragma unroll
        for (int k = 0; k < 16; ++k) tot += red[k];
        out[0] = tot * (1.0f / 1024.0f);
    }
}

extern "C" void kernel_launch(void* const* d_in, const int* in_sizes, int n_in,
                              void* d_out, int out_size, void* d_ws, size_t ws_size,
                              hipStream_t stream) {
    (void)in_sizes; (void)n_in; (void)out_size; (void)ws_size;
    const float* emb = (const float*)d_in[0];   // 64 x 512
    const float* xyz = (const float*)d_in[1];   // 64 x 256 x 3
    float* cdHalf = (float*)d_ws;               // 992 directional halves
    float* dots   = cdHalf + 1024;              // 32x32
    float* out    = (float*)d_out;

    hipLaunchKernelGGL(pairs_kernel, dim3(280), dim3(256), 0, stream, emb, xyz, cdHalf, dots);
    hipLaunchKernelGGL(finish_kernel, dim3(1), dim3(1024), 0, stream, cdHalf, dots, out);
}